// Round 2
// baseline (292.432 us; speedup 1.0000x reference)
//
#include <hip/hip_runtime.h>
#include <cstdint>
#include <cstddef>

// ---------------------------------------------------------------------------
// QuantumNeuralNetwork fused pipeline for MI355X (gfx950)
//   K1: h = x @ w_in.T + b_in          (HBM-bound: 134 MB read)
//   K2: LN/tanh/circuit/noise/mlp1 -> out = relu(.)@w2.T + b2  (67 MB write)
// Noise replicates JAX *partitionable* threefry (default since jax 0.5):
//   bits(i) = o0 ^ o1 of threefry2x32(key=(0,1234), count=(hi=0, lo=i))
// then uniform->erfinv normal exactly as XLA.
// ---------------------------------------------------------------------------

__device__ __forceinline__ uint32_t rotl32(uint32_t x, int r) {
  return (x << r) | (x >> (32 - r));
}

// JAX threefry2x32, 20 rounds, key injections per jax/_src/prng.py
__device__ __forceinline__ void threefry2x32(uint32_t k0, uint32_t k1,
                                             uint32_t& x0, uint32_t& x1) {
  const uint32_t k2 = k0 ^ k1 ^ 0x1BD11BDAu;
  x0 += k0; x1 += k1;
#define TF_R(r) { x0 += x1; x1 = rotl32(x1, (r)); x1 ^= x0; }
  TF_R(13) TF_R(15) TF_R(26) TF_R(6)
  x0 += k1; x1 += k2 + 1u;
  TF_R(17) TF_R(29) TF_R(16) TF_R(24)
  x0 += k2; x1 += k0 + 2u;
  TF_R(13) TF_R(15) TF_R(26) TF_R(6)
  x0 += k0; x1 += k1 + 3u;
  TF_R(17) TF_R(29) TF_R(16) TF_R(24)
  x0 += k1; x1 += k2 + 4u;
  TF_R(13) TF_R(15) TF_R(26) TF_R(6)
  x0 += k2; x1 += k0 + 5u;
#undef TF_R
}

// XLA ErfInv32 (Giles polynomial) — matches jax.lax.erf_inv at f32
__device__ __forceinline__ float erfinv_xla(float x) {
  float w = -log1pf(-x * x);
  float p;
  if (w < 5.0f) {
    w -= 2.5f;
    p = 2.81022636e-08f;
    p = fmaf(p, w, 3.43273939e-07f);
    p = fmaf(p, w, -3.5233877e-06f);
    p = fmaf(p, w, -4.39150654e-06f);
    p = fmaf(p, w, 0.00021858087f);
    p = fmaf(p, w, -0.00125372503f);
    p = fmaf(p, w, -0.00417768164f);
    p = fmaf(p, w, 0.246640727f);
    p = fmaf(p, w, 1.50140941f);
  } else {
    w = sqrtf(w) - 3.0f;
    p = -0.000200214257f;
    p = fmaf(p, w, 0.000100950558f);
    p = fmaf(p, w, 0.00134934322f);
    p = fmaf(p, w, -0.00367342844f);
    p = fmaf(p, w, 0.00573950773f);
    p = fmaf(p, w, -0.0076224613f);
    p = fmaf(p, w, 0.00943887047f);
    p = fmaf(p, w, 1.00167406f);
    p = fmaf(p, w, 2.83297682f);
  }
  return p * x;
}

// ---------------------------------------------------------------------------
// K1: h[32768][12] = x[32768][1024] @ w_in.T + b_in
// wave layout: r = lane>>4 (4 rows), kc = lane&15 (16 k-lanes of float4)
// w_in staged in LDS (48 KB); x streamed coalesced; shfl_xor(1,2,4,8) reduce.
// grid 512 x block 256; 64 rows/block; 3 blocks/CU (LDS-limited).
// ---------------------------------------------------------------------------
__global__ __launch_bounds__(256, 3)
void qnn_gemm_in(const float* __restrict__ x, const float* __restrict__ w_in,
                 const float* __restrict__ b_in, float* __restrict__ h) {
  __shared__ float wl[12 * 1024];
  {
    const float4* ws = (const float4*)w_in;
    float4* wd = (float4*)wl;
#pragma unroll
    for (int j = 0; j < 12; ++j) wd[threadIdx.x + 256 * j] = ws[threadIdx.x + 256 * j];
  }
  __syncthreads();

  const int wave = threadIdx.x >> 6;
  const int lane = threadIdx.x & 63;
  const int r    = lane >> 4;   // row within quad
  const int kc   = lane & 15;   // k-chunk lane

  float bq[12];
#pragma unroll
  for (int q = 0; q < 12; ++q) bq[q] = b_in[q];

  for (int it = 0; it < 4; ++it) {
    const int row = (blockIdx.x << 6) + (it << 4) + (wave << 2) + r;
    const float4* xr = (const float4*)(x + (size_t)row * 1024);

    float acc[12];
#pragma unroll
    for (int q = 0; q < 12; ++q) acc[q] = 0.0f;

#pragma unroll 4
    for (int ks = 0; ks < 16; ++ks) {
      const float4 xv = xr[(ks << 4) + kc];
#pragma unroll
      for (int q = 0; q < 12; ++q) {
        const float4 wv = *(const float4*)&wl[q * 1024 + (ks << 6) + (kc << 2)];
        acc[q] += xv.x * wv.x + xv.y * wv.y + xv.z * wv.z + xv.w * wv.w;
      }
    }

    // reduce over the 16 kc lanes (bits 0..3 of lane id)
#pragma unroll
    for (int q = 0; q < 12; ++q) {
      float v = acc[q];
      v += __shfl_xor(v, 1);
      v += __shfl_xor(v, 2);
      v += __shfl_xor(v, 4);
      v += __shfl_xor(v, 8);
      acc[q] = v + bq[q];
    }
    if (kc == 0) {
      float* hp = h + (size_t)row * 12;
      *(float4*)(hp + 0) = make_float4(acc[0], acc[1], acc[2], acc[3]);
      *(float4*)(hp + 4) = make_float4(acc[4], acc[5], acc[6], acc[7]);
      *(float4*)(hp + 8) = make_float4(acc[8], acc[9], acc[10], acc[11]);
    }
  }
}

// ---------------------------------------------------------------------------
// K2: per-row LN+tanh+circuit+noise+mlp1 (64 rows/block, 16 lanes/wave active),
// then block-wide output GEMM out[64][512] with w2 fragments in registers.
// grid 512 x block 256.
// ---------------------------------------------------------------------------
__global__ __launch_bounds__(256, 2)
void qnn_tail(const float* __restrict__ h_in,
              const float* __restrict__ ln_g, const float* __restrict__ ln_b,
              const float* __restrict__ rot,  const float* __restrict__ ent,
              const float* __restrict__ w1,   const float* __restrict__ b1,
              const float* __restrict__ w2,   const float* __restrict__ b2,
              const float* __restrict__ meas, float* __restrict__ out) {
  __shared__ float w2s[512 * 12];
  __shared__ float b2s[512];
  __shared__ float hid[64 * 12];
  __shared__ float rot0[8][12], sr1[8][12], cr2[8][12], cen[8][12];
  __shared__ float tmb[12], w1s[144], b1s[12];

  const int t = threadIdx.x;

  {  // staging
    const float4* s = (const float4*)w2;
    float4* d = (float4*)w2s;
#pragma unroll
    for (int j = 0; j < 6; ++j) d[t + 256 * j] = s[t + 256 * j];
    if (t < 128) ((float4*)b2s)[t] = ((const float4*)b2)[t];
    if (t < 96) {
      const int l = t / 12, q = t % 12, base = (l * 12 + q) * 3;
      rot0[l][q] = rot[base + 0];
      sr1[l][q]  = sinf(rot[base + 1] * 0.5f);
      cr2[l][q]  = cosf(rot[base + 2] * 0.5f);
    }
    if (t >= 128 && t < 216) {
      const int i = t - 128, l = i / 11, q = i % 11;
      cen[l][q] = 1.0f / (1.0f + expf(-ent[l * 11 + q]));
    }
    if (t >= 216 && t < 228) tmb[t - 216] = tanhf(meas[t - 216]);
    if (t >= 228 && t < 240) b1s[t - 228] = b1[t - 228];
    if (t < 144) w1s[t] = w1[t];
  }
  __syncthreads();

  const int wave = t >> 6, lane = t & 63;
  if (lane < 16) {
    const int rl  = (wave << 4) + lane;            // 0..63
    const int row = (blockIdx.x << 6) + rl;

    const float* hp = h_in + (size_t)row * 12;
    const float4 a0 = *(const float4*)(hp + 0);
    const float4 a1 = *(const float4*)(hp + 4);
    const float4 a2 = *(const float4*)(hp + 8);
    float hv[12] = {a0.x, a0.y, a0.z, a0.w, a1.x, a1.y, a1.z, a1.w,
                    a2.x, a2.y, a2.z, a2.w};

    float s = 0.0f;
#pragma unroll
    for (int q = 0; q < 12; ++q) s += hv[q];
    const float mu = s / 12.0f;
    float var = 0.0f;
#pragma unroll
    for (int q = 0; q < 12; ++q) { const float d = hv[q] - mu; var += d * d; }
    var /= 12.0f;
    const float inv = 1.0f / sqrtf(var + 1e-5f);

    float enc[12];
#pragma unroll
    for (int q = 0; q < 12; ++q) {
      const float n = (hv[q] - mu) * inv * ln_g[q] + ln_b[q];
      enc[q] = tanhf(n) * 3.14159265358979f;
    }

    float st[12];
#pragma unroll
    for (int q = 0; q < 12; ++q) st[q] = 0.0f;
#pragma unroll
    for (int l = 0; l < 8; ++l) {
#pragma unroll
      for (int q = 0; q < 12; ++q) {
        const float rx = enc[q] + rot0[l][q];
        st[q] = st[q] * cosf(rx * 0.5f) + sr1[l][q];
        st[q] *= cr2[l][q];
      }
      if (l < 7) {
        float ns[12];
#pragma unroll
        for (int i = 0; i < 11; ++i) {
          const float c = cen[l][i];
          ns[i] = st[i] * (1.0f - c) + st[i + 1] * c;
        }
        { const float c = cen[l][10]; ns[11] = st[11] * (1.0f - c) + st[10] * c; }
#pragma unroll
        for (int q = 0; q < 12; ++q) st[q] = ns[q];
      }
    }

    // measurement noise: JAX partitionable threefry.
    // flat idx i -> 64-bit count (hi=0, lo=i); bits = out0 ^ out1.
    const uint32_t base = (uint32_t)row * 12u;
    float m[12];
#pragma unroll
    for (int q = 0; q < 12; ++q) {
      uint32_t x0 = 0u;                    // count high word (size < 2^32)
      uint32_t x1 = base + (uint32_t)q;    // count low word = flat index
      threefry2x32(0u, 1234u, x0, x1);
      const uint32_t bits = x0 ^ x1;       // fold 64 output bits -> 32
      const float u01 = __uint_as_float((bits >> 9) | 0x3F800000u) - 1.0f;
      float u = u01 * 2.0f + (-0.99999994f);   // hi-lo == 2.0f exactly
      u = fmaxf(-0.99999994f, u);
      const float nrm = 1.41421356237f * erfinv_xla(u);
      m[q] = tanhf(st[q] * tmb[q] + nrm * 0.01f);
    }

    float* hd = &hid[rl * 12];
#pragma unroll
    for (int j = 0; j < 12; ++j) {
      float a = b1s[j];
#pragma unroll
      for (int q = 0; q < 12; ++q) a = fmaf(m[q], w1s[j * 12 + q], a);
      hd[j] = fmaxf(a, 0.0f);
    }
  }
  __syncthreads();

  // output GEMM: thread t owns cols t and t+256 across 64 rows
  float wa[12], wb[12];
#pragma unroll
  for (int q = 0; q < 12; ++q) {
    wa[q] = w2s[t * 12 + q];
    wb[q] = w2s[(t + 256) * 12 + q];
  }
  const float ba = b2s[t], bb = b2s[t + 256];
  float* ob = out + (size_t)blockIdx.x * 64 * 512;
  for (int rr = 0; rr < 64; ++rr) {
    const float4 h0 = *(const float4*)&hid[rr * 12 + 0];
    const float4 h1 = *(const float4*)&hid[rr * 12 + 4];
    const float4 h2 = *(const float4*)&hid[rr * 12 + 8];
    const float hvv[12] = {h0.x, h0.y, h0.z, h0.w, h1.x, h1.y, h1.z, h1.w,
                           h2.x, h2.y, h2.z, h2.w};
    float a = ba, b = bb;
#pragma unroll
    for (int q = 0; q < 12; ++q) {
      a = fmaf(hvv[q], wa[q], a);
      b = fmaf(hvv[q], wb[q], b);
    }
    ob[rr * 512 + t] = a;
    ob[rr * 512 + 256 + t] = b;
  }
}

extern "C" void kernel_launch(void* const* d_in, const int* in_sizes, int n_in,
                              void* d_out, int out_size, void* d_ws, size_t ws_size,
                              hipStream_t stream) {
  const float* x    = (const float*)d_in[0];
  const float* w_in = (const float*)d_in[1];
  const float* b_in = (const float*)d_in[2];
  const float* ln_g = (const float*)d_in[3];
  const float* ln_b = (const float*)d_in[4];
  const float* rot  = (const float*)d_in[5];
  const float* ent  = (const float*)d_in[6];
  const float* w1   = (const float*)d_in[7];
  const float* b1   = (const float*)d_in[8];
  const float* w2   = (const float*)d_in[9];
  const float* b2   = (const float*)d_in[10];
  const float* mb   = (const float*)d_in[11];
  float* outp = (float*)d_out;
  float* h    = (float*)d_ws;  // 32768*12 floats = 1.57 MB scratch

  qnn_gemm_in<<<512, 256, 0, stream>>>(x, w_in, b_in, h);
  qnn_tail<<<512, 256, 0, stream>>>(h, ln_g, ln_b, rot, ent, w1, b1, w2, b2, mb, outp);
}

// Round 7
// 249.974 us; speedup vs baseline: 1.1698x; 1.1698x over previous
//
#include <hip/hip_runtime.h>
#include <cstdint>
#include <cstddef>

// ---------------------------------------------------------------------------
// QuantumNeuralNetwork fused pipeline for MI355X (gfx950)  — R2 (resubmit R6)
//   K1: h = x @ w_in.T + b_in    512-thread blocks, ping-pong prefetch,
//                                16 waves/CU (was 8). HBM floor ~21 us.
//   K2: LN/tanh/circuit/noise/mlp1/out-GEMM, grid 1024 (4 blocks/CU),
//       circuit parallelized lane-per-(row,qubit).
// Noise = JAX partitionable threefry: bits(i) = o0^o1 of
// threefry2x32(key=(0,1234), count=(0,i)), then XLA uniform->erfinv normal.
// ---------------------------------------------------------------------------

__device__ __forceinline__ uint32_t rotl32(uint32_t x, int r) {
  return (x << r) | (x >> (32 - r));
}

__device__ __forceinline__ void threefry2x32(uint32_t k0, uint32_t k1,
                                             uint32_t& x0, uint32_t& x1) {
  const uint32_t k2 = k0 ^ k1 ^ 0x1BD11BDAu;
  x0 += k0; x1 += k1;
#define TF_R(r) { x0 += x1; x1 = rotl32(x1, (r)); x1 ^= x0; }
  TF_R(13) TF_R(15) TF_R(26) TF_R(6)
  x0 += k1; x1 += k2 + 1u;
  TF_R(17) TF_R(29) TF_R(16) TF_R(24)
  x0 += k2; x1 += k0 + 2u;
  TF_R(13) TF_R(15) TF_R(26) TF_R(6)
  x0 += k0; x1 += k1 + 3u;
  TF_R(17) TF_R(29) TF_R(16) TF_R(24)
  x0 += k1; x1 += k2 + 4u;
  TF_R(13) TF_R(15) TF_R(26) TF_R(6)
  x0 += k2; x1 += k0 + 5u;
#undef TF_R
}

__device__ __forceinline__ float erfinv_xla(float x) {
  float w = -log1pf(-x * x);
  float p;
  if (w < 5.0f) {
    w -= 2.5f;
    p = 2.81022636e-08f;
    p = fmaf(p, w, 3.43273939e-07f);
    p = fmaf(p, w, -3.5233877e-06f);
    p = fmaf(p, w, -4.39150654e-06f);
    p = fmaf(p, w, 0.00021858087f);
    p = fmaf(p, w, -0.00125372503f);
    p = fmaf(p, w, -0.00417768164f);
    p = fmaf(p, w, 0.246640727f);
    p = fmaf(p, w, 1.50140941f);
  } else {
    w = sqrtf(w) - 3.0f;
    p = -0.000200214257f;
    p = fmaf(p, w, 0.000100950558f);
    p = fmaf(p, w, 0.00134934322f);
    p = fmaf(p, w, -0.00367342844f);
    p = fmaf(p, w, 0.00573950773f);
    p = fmaf(p, w, -0.0076224613f);
    p = fmaf(p, w, 0.00943887047f);
    p = fmaf(p, w, 1.00167406f);
    p = fmaf(p, w, 2.83297682f);
  }
  return p * x;
}

// ---------------------------------------------------------------------------
// K1: h[32768][12] = x @ w_in.T + b_in.
// block 512 thr (8 waves), 64 rows/block, grid 512 -> 2 blocks/CU = 16 waves.
// wave = 4 rows x 16 kc lanes; 2 row-iters; A/B ping-pong float4 prefetch.
// ---------------------------------------------------------------------------
__global__ __launch_bounds__(512, 4)
void qnn_gemm_in(const float* __restrict__ x, const float* __restrict__ w_in,
                 const float* __restrict__ b_in, float* __restrict__ h) {
  __shared__ float wl[12 * 1024];
  {
    const float4* ws = (const float4*)w_in;
    float4* wd = (float4*)wl;
#pragma unroll
    for (int j = 0; j < 6; ++j) wd[threadIdx.x + 512 * j] = ws[threadIdx.x + 512 * j];
  }
  __syncthreads();

  const int wave = threadIdx.x >> 6;
  const int lane = threadIdx.x & 63;
  const int r    = lane >> 4;
  const int kc   = lane & 15;

  float bq[12];
#pragma unroll
  for (int q = 0; q < 12; ++q) bq[q] = b_in[q];

#pragma unroll
  for (int it = 0; it < 2; ++it) {
    const int row = (blockIdx.x << 6) + (wave << 3) + (it << 2) + r;
    const float4* xr = (const float4*)(x + (size_t)row * 1024);

    float4 A[4], B[4];
#pragma unroll
    for (int i = 0; i < 4; ++i) A[i] = xr[((0 + i) << 4) + kc];
#pragma unroll
    for (int i = 0; i < 4; ++i) B[i] = xr[((4 + i) << 4) + kc];

    float acc[12];
#pragma unroll
    for (int q = 0; q < 12; ++q) acc[q] = 0.0f;

    // group A: ks 0..3, then reload A <- ks 8..11
#pragma unroll
    for (int i = 0; i < 4; ++i) {
      const int ks = i;
#pragma unroll
      for (int q = 0; q < 12; ++q) {
        const float4 wv = *(const float4*)&wl[q * 1024 + (ks << 6) + (kc << 2)];
        acc[q] += A[i].x * wv.x + A[i].y * wv.y + A[i].z * wv.z + A[i].w * wv.w;
      }
    }
#pragma unroll
    for (int i = 0; i < 4; ++i) A[i] = xr[((8 + i) << 4) + kc];

    // group B: ks 4..7, then reload B <- ks 12..15
#pragma unroll
    for (int i = 0; i < 4; ++i) {
      const int ks = 4 + i;
#pragma unroll
      for (int q = 0; q < 12; ++q) {
        const float4 wv = *(const float4*)&wl[q * 1024 + (ks << 6) + (kc << 2)];
        acc[q] += B[i].x * wv.x + B[i].y * wv.y + B[i].z * wv.z + B[i].w * wv.w;
      }
    }
#pragma unroll
    for (int i = 0; i < 4; ++i) B[i] = xr[((12 + i) << 4) + kc];

    // group A': ks 8..11
#pragma unroll
    for (int i = 0; i < 4; ++i) {
      const int ks = 8 + i;
#pragma unroll
      for (int q = 0; q < 12; ++q) {
        const float4 wv = *(const float4*)&wl[q * 1024 + (ks << 6) + (kc << 2)];
        acc[q] += A[i].x * wv.x + A[i].y * wv.y + A[i].z * wv.z + A[i].w * wv.w;
      }
    }
    // group B': ks 12..15
#pragma unroll
    for (int i = 0; i < 4; ++i) {
      const int ks = 12 + i;
#pragma unroll
      for (int q = 0; q < 12; ++q) {
        const float4 wv = *(const float4*)&wl[q * 1024 + (ks << 6) + (kc << 2)];
        acc[q] += B[i].x * wv.x + B[i].y * wv.y + B[i].z * wv.z + B[i].w * wv.w;
      }
    }

#pragma unroll
    for (int q = 0; q < 12; ++q) {
      float v = acc[q];
      v += __shfl_xor(v, 1);
      v += __shfl_xor(v, 2);
      v += __shfl_xor(v, 4);
      v += __shfl_xor(v, 8);
      acc[q] = v + bq[q];
    }
    if (kc == 0) {
      float* hp = h + (size_t)row * 12;
      *(float4*)(hp + 0) = make_float4(acc[0], acc[1], acc[2], acc[3]);
      *(float4*)(hp + 4) = make_float4(acc[4], acc[5], acc[6], acc[7]);
      *(float4*)(hp + 8) = make_float4(acc[8], acc[9], acc[10], acc[11]);
    }
  }
}

// ---------------------------------------------------------------------------
// K2: grid 1024 x block 256, 32 rows/block (4 blocks/CU).
// Circuit: lane-per-(row,qubit): 16-lane groups, q = lane&15 (q<12 active),
// 4 rows/wave/pass, 2 passes. Entangle via __shfl(lane+/-1), LN via shfl_xor,
// mlp1 via 12 shfl broadcasts. Out-GEMM: thread t -> cols t, t+256.
// ---------------------------------------------------------------------------
__global__ __launch_bounds__(256, 4)
void qnn_tail(const float* __restrict__ h_in,
              const float* __restrict__ ln_g, const float* __restrict__ ln_b,
              const float* __restrict__ rot,  const float* __restrict__ ent,
              const float* __restrict__ w1,   const float* __restrict__ b1,
              const float* __restrict__ w2,   const float* __restrict__ b2,
              const float* __restrict__ meas, float* __restrict__ out) {
  __shared__ float w2s[512 * 12];
  __shared__ float b2s[512];
  __shared__ float hid[32 * 12];
  __shared__ float rot0s[8 * 16], sr1s[8 * 16], cr2s[8 * 16], cens[8 * 16];
  __shared__ float tmbs[16], w1T[12 * 16], b1s[16], lgs[16], lbs[16];

  const int t = threadIdx.x;

  {  // staging
    const float4* s = (const float4*)w2;
    float4* d = (float4*)w2s;
#pragma unroll
    for (int j = 0; j < 6; ++j) d[t + 256 * j] = s[t + 256 * j];
    if (t < 128) ((float4*)b2s)[t] = ((const float4*)b2)[t];
    if (t < 96) {
      const int l = t / 12, q = t % 12, base = (l * 12 + q) * 3;
      rot0s[l * 16 + q] = rot[base + 0];
      sr1s[l * 16 + q]  = sinf(rot[base + 1] * 0.5f);
      cr2s[l * 16 + q]  = cosf(rot[base + 2] * 0.5f);
    }
    if (t >= 96 && t < 184) {
      const int i = t - 96, l = i / 11, q = i % 11;
      cens[l * 16 + q] = 1.0f / (1.0f + expf(-ent[l * 11 + q]));
    }
    if (t >= 184 && t < 196) tmbs[t - 184] = tanhf(meas[t - 184]);
    if (t >= 196 && t < 208) b1s[t - 196] = b1[t - 196];
    if (t >= 208 && t < 220) lgs[t - 208] = ln_g[t - 208];
    if (t >= 220 && t < 232) lbs[t - 220] = ln_b[t - 220];
    if (t < 144) { const int j = t / 12, q = t % 12; w1T[q * 16 + j] = w1[t]; }
  }
  __syncthreads();

  // out-GEMM weight fragments (hoisted; overlaps with circuit scheduling)
  float wa[12], wb[12];
#pragma unroll
  for (int q = 0; q < 12; ++q) {
    wa[q] = w2s[t * 12 + q];
    wb[q] = w2s[(t + 256) * 12 + q];
  }
  const float ba = b2s[t], bb = b2s[t + 256];

  const int lane = t & 63;
  const int wv   = t >> 6;
  const int grp  = lane >> 4;
  const int q    = lane & 15;        // active q < 12
  const int gb   = lane & 48;        // group base lane
  const bool act = (q < 12);
  const int cidx = (q == 11) ? 10 : q;

#pragma unroll
  for (int pass = 0; pass < 2; ++pass) {
    const int rl  = (pass << 4) + (wv << 2) + grp;   // 0..31
    const int row = (blockIdx.x << 5) + rl;

    float hq = act ? h_in[(size_t)row * 12 + q] : 0.0f;

    // layernorm over the 16-lane group (q>=12 contribute 0)
    float s = hq;
    s += __shfl_xor(s, 1); s += __shfl_xor(s, 2);
    s += __shfl_xor(s, 4); s += __shfl_xor(s, 8);
    const float mu = s * (1.0f / 12.0f);
    float d = act ? (hq - mu) : 0.0f;
    float v2 = d * d;
    v2 += __shfl_xor(v2, 1); v2 += __shfl_xor(v2, 2);
    v2 += __shfl_xor(v2, 4); v2 += __shfl_xor(v2, 8);
    const float inv = 1.0f / sqrtf(v2 * (1.0f / 12.0f) + 1e-5f);

    const float n   = d * inv * lgs[q] + lbs[q];
    const float enc = tanhf(n) * 3.14159265358979f;

    float st = 0.0f;
#pragma unroll
    for (int l = 0; l < 8; ++l) {
      const float rx = enc + rot0s[l * 16 + q];
      st = st * cosf(rx * 0.5f) + sr1s[l * 16 + q];
      st *= cr2s[l * 16 + q];
      if (l < 7) {
        const float stn = __shfl(st, lane + 1);
        const float stp = __shfl(st, lane - 1);
        const float c   = cens[l * 16 + cidx];
        const float other = (q == 11) ? stp : stn;
        st = st * (1.0f - c) + other * c;
      }
    }

    // noise (JAX partitionable threefry) + measurement tanh
    uint32_t x0 = 0u, x1 = (uint32_t)row * 12u + (uint32_t)q;
    threefry2x32(0u, 1234u, x0, x1);
    const uint32_t bits = x0 ^ x1;
    const float u01 = __uint_as_float((bits >> 9) | 0x3F800000u) - 1.0f;
    float u = u01 * 2.0f + (-0.99999994f);
    u = fmaxf(-0.99999994f, u);
    const float nrm = 1.41421356237f * erfinv_xla(u);
    const float m = tanhf(st * tmbs[q] + nrm * 0.01f);

    // mlp1: lane j(==q) computes hidden j for its row
    float acc1 = b1s[q];
#pragma unroll
    for (int qq = 0; qq < 12; ++qq) {
      const float mq = __shfl(m, gb + qq);
      acc1 = fmaf(mq, w1T[qq * 16 + q], acc1);
    }
    if (act) hid[rl * 12 + q] = fmaxf(acc1, 0.0f);
  }
  __syncthreads();

  // out-GEMM: 32 rows x 512 cols
  float* ob = out + (size_t)blockIdx.x * 32 * 512;
  for (int rr = 0; rr < 32; ++rr) {
    const float4 h0 = *(const float4*)&hid[rr * 12 + 0];
    const float4 h1 = *(const float4*)&hid[rr * 12 + 4];
    const float4 h2 = *(const float4*)&hid[rr * 12 + 8];
    const float hvv[12] = {h0.x, h0.y, h0.z, h0.w, h1.x, h1.y, h1.z, h1.w,
                           h2.x, h2.y, h2.z, h2.w};
    float a = ba, b = bb;
#pragma unroll
    for (int qq = 0; qq < 12; ++qq) {
      a = fmaf(hvv[qq], wa[qq], a);
      b = fmaf(hvv[qq], wb[qq], b);
    }
    ob[rr * 512 + t] = a;
    ob[rr * 512 + 256 + t] = b;
  }
}

extern "C" void kernel_launch(void* const* d_in, const int* in_sizes, int n_in,
                              void* d_out, int out_size, void* d_ws, size_t ws_size,
                              hipStream_t stream) {
  const float* x    = (const float*)d_in[0];
  const float* w_in = (const float*)d_in[1];
  const float* b_in = (const float*)d_in[2];
  const float* ln_g = (const float*)d_in[3];
  const float* ln_b = (const float*)d_in[4];
  const float* rot  = (const float*)d_in[5];
  const float* ent  = (const float*)d_in[6];
  const float* w1   = (const float*)d_in[7];
  const float* b1   = (const float*)d_in[8];
  const float* w2   = (const float*)d_in[9];
  const float* b2   = (const float*)d_in[10];
  const float* mb   = (const float*)d_in[11];
  float* outp = (float*)d_out;
  float* h    = (float*)d_ws;  // 32768*12 floats = 1.57 MB scratch

  qnn_gemm_in<<<512, 512, 0, stream>>>(x, w_in, b_in, h);
  qnn_tail<<<1024, 256, 0, stream>>>(h, ln_g, ln_b, rot, ent, w1, b1, w2, b2, mb, outp);
}